// Round 8
// baseline (766.296 us; speedup 1.0000x reference)
//
#include <hip/hip_runtime.h>

#define DIM     64
#define N_EMBED 512
#define N_ROWS  131072   // 32*64*64
#define XPAD    132      // row pitch (bank stagger)
#define CHUNK   4096     // vq_seg scan chunk (queue capacity)

// ---------- prep: ||e_j||^2 and (optional) embed transpose ----------
__global__ void prep_kernel(const float* __restrict__ embed,
                            float* __restrict__ se,
                            float* __restrict__ embed_t,
                            int do_et) {
    int j = blockIdx.x * blockDim.x + threadIdx.x;   // 0..511
    if (j >= N_EMBED) return;
    float s = 0.f;
#pragma unroll
    for (int d = 0; d < DIM; d += 4) {
        float b0 = embed[(d + 0) * N_EMBED + j];
        float b1 = embed[(d + 1) * N_EMBED + j];
        float b2 = embed[(d + 2) * N_EMBED + j];
        float b3 = embed[(d + 3) * N_EMBED + j];
        s = fmaf(b0, b0, s); s = fmaf(b1, b1, s);
        s = fmaf(b2, b2, s); s = fmaf(b3, b3, s);
        if (do_et) {
            float4 v; v.x = b0; v.y = b1; v.z = b2; v.w = b3;
            *reinterpret_cast<float4*>(&embed_t[j * DIM + d]) = v;
        }
    }
    se[j] = s;
}

// ---------- assign: LDS-tiled fp32 GEMM-argmin (byte-identical to round 6) ----------
__launch_bounds__(256, 2)
__global__ void vq_assign(const float* __restrict__ input,
                          const float* __restrict__ embed,
                          const float* __restrict__ se,
                          float* __restrict__ out_ind,
                          int*   __restrict__ ind) {
    __shared__ float Xs[64][XPAD];   // [k][row]
    __shared__ float Es[64][XPAD];   // [k][swizzled col]; reused for final reduce
    __shared__ float sxs[128];

    const int t    = threadIdx.x;
    const int row0 = blockIdx.x * 128;
    const int tr   = t >> 4;   // 0..15
    const int tc   = t & 15;   // 0..15
    const int bx   = ((tc >> 2) & 1) * 4;   // XOR on read

    // ---- stage X transposed: Xs[k][i] = input[(row0+i)*64 + k] ----
#pragma unroll
    for (int ph = 0; ph < 8; ++ph) {
        int idx = ph * 256 + t;      // 0..2047
        int row = idx >> 4;          // 0..127
        int kq  = idx & 15;          // 0..15
        float4 v = *reinterpret_cast<const float4*>(
            &input[(size_t)(row0 + row) * 64 + kq * 4]);
        Xs[kq * 4 + 0][row] = v.x;
        Xs[kq * 4 + 1][row] = v.y;
        Xs[kq * 4 + 2][row] = v.z;
        Xs[kq * 4 + 3][row] = v.w;
    }
    __syncthreads();

    // ---- sx per row ----
    if (t < 128) {
        float s = 0.f;
#pragma unroll 8
        for (int k = 0; k < 64; ++k) { float x = Xs[k][t]; s = fmaf(x, x, s); }
        sxs[t] = s;
    }

    float bestd[8], sx[8];
    int   bestj[8];
#pragma unroll
    for (int r = 0; r < 8; ++r) { bestd[r] = INFINITY; bestj[r] = 0; }

    for (int chunk = 0; chunk < 4; ++chunk) {
        const int ccb = chunk * 128;
        __syncthreads();   // prev k-loop done reading Es (also fences sxs/Xs)
#pragma unroll
        for (int ph = 0; ph < 8; ++ph) {
            int idx = ph * 256 + t;  // 0..2047
            int k   = idx >> 5;      // 0..63
            int cq  = idx & 31;      // 0..31
            float4 v = *reinterpret_cast<const float4*>(
                &embed[k * N_EMBED + ccb + cq * 4]);
            // XOR swizzle: block base c=cq*4 -> c ^ (bit5(c)*4)
            *reinterpret_cast<float4*>(&Es[k][(cq * 4) ^ (((cq >> 3) & 1) * 4)]) = v;
        }
        __syncthreads();
        if (chunk == 0) {
#pragma unroll
            for (int r = 0; r < 8; ++r) sx[r] = sxs[tr * 8 + r];
        }

        float acc[8][8];
#pragma unroll
        for (int r = 0; r < 8; ++r)
#pragma unroll
            for (int c = 0; c < 8; ++c) acc[r][c] = 0.f;

#pragma unroll 2
        for (int k = 0; k < 64; ++k) {
            float a[8], b[8];
            *reinterpret_cast<float4*>(&a[0]) = *reinterpret_cast<const float4*>(&Xs[k][tr * 8]);
            *reinterpret_cast<float4*>(&a[4]) = *reinterpret_cast<const float4*>(&Xs[k][tr * 8 + 4]);
            *reinterpret_cast<float4*>(&b[0]) = *reinterpret_cast<const float4*>(&Es[k][(tc * 8) ^ bx]);
            *reinterpret_cast<float4*>(&b[4]) = *reinterpret_cast<const float4*>(&Es[k][(tc * 8 + 4) ^ bx]);
#pragma unroll
            for (int r = 0; r < 8; ++r)
#pragma unroll
                for (int c = 0; c < 8; ++c)
                    acc[r][c] = fmaf(a[r], b[c], acc[r][c]);
        }

        // finalize this chunk: scan cols in increasing j (first-wins ties)
#pragma unroll
        for (int c = 0; c < 8; ++c) {
            int j = ccb + tc * 8 + c;
            float sej = se[j];
#pragma unroll
            for (int r = 0; r < 8; ++r) {
                float d = (sx[r] - 2.f * acc[r][c]) + sej;
                if (d < bestd[r]) { bestd[r] = d; bestj[r] = j; }
            }
        }
    }

    // ---- cross-thread argmin reduce (lexicographic (d, j) == global first-min) ----
    __syncthreads();
    float* rd = &Es[0][0];                 // [128][17]
    int*   rj = (int*)(rd + 128 * 17);     // [128][17]
#pragma unroll
    for (int r = 0; r < 8; ++r) {
        rd[(tr * 8 + r) * 17 + tc] = bestd[r];
        rj[(tr * 8 + r) * 17 + tc] = bestj[r];
    }
    __syncthreads();
    if (t < 128) {
        float bd = rd[t * 17 + 0];
        int   bj = rj[t * 17 + 0];
#pragma unroll
        for (int w = 1; w < 16; ++w) {
            float dw = rd[t * 17 + w];
            int   jw = rj[t * 17 + w];
            if (dw < bd || (dw == bd && jw < bj)) { bd = dw; bj = jw; }
        }
        out_ind[row0 + t] = (float)bj;
        ind[row0 + t]     = bj;
    }
}

// ---------- quant: streaming quantize + diff (no LDS table, high occupancy) ----------
__launch_bounds__(256)
__global__ void vq_quant(const float* __restrict__ input,
                         const float* __restrict__ embed,
                         const float* __restrict__ embed_t,
                         const int* __restrict__ ind,
                         float* __restrict__ out_q,
                         double* __restrict__ diff_acc,
                         int have_et) {
    const int i = blockIdx.x * 256 + threadIdx.x;
    const int j = ind[i];
    const float* rp = input + (size_t)i * DIM;
    float* oq = out_q + (size_t)i * DIM;
    float dsum = 0.f;

    if (have_et) {
        const float* qp = embed_t + (size_t)j * DIM;
#pragma unroll
        for (int d = 0; d < DIM; d += 4) {
            float4 v = *reinterpret_cast<const float4*>(rp + d);
            float4 q = *reinterpret_cast<const float4*>(qp + d);
            float t0 = q.x - v.x, t1 = q.y - v.y, t2 = q.z - v.z, t3 = q.w - v.w;
            float4 o;
            o.x = v.x + t0; o.y = v.y + t1; o.z = v.z + t2; o.w = v.w + t3;
            *reinterpret_cast<float4*>(oq + d) = o;
            dsum = fmaf(t0, t0, dsum); dsum = fmaf(t1, t1, dsum);
            dsum = fmaf(t2, t2, dsum); dsum = fmaf(t3, t3, dsum);
        }
    } else {
#pragma unroll
        for (int d = 0; d < DIM; d += 4) {
            float4 v = *reinterpret_cast<const float4*>(rp + d);
            float q0 = embed[(d + 0) * N_EMBED + j];
            float q1 = embed[(d + 1) * N_EMBED + j];
            float q2 = embed[(d + 2) * N_EMBED + j];
            float q3 = embed[(d + 3) * N_EMBED + j];
            float t0 = q0 - v.x, t1 = q1 - v.y, t2 = q2 - v.z, t3 = q3 - v.w;
            float4 o;
            o.x = v.x + t0; o.y = v.y + t1; o.z = v.z + t2; o.w = v.w + t3;
            *reinterpret_cast<float4*>(oq + d) = o;
            dsum = fmaf(t0, t0, dsum); dsum = fmaf(t1, t1, dsum);
            dsum = fmaf(t2, t2, dsum); dsum = fmaf(t3, t3, dsum);
        }
    }

    // wave -> block reduce, one f64 atomic per block
    for (int off = 32; off > 0; off >>= 1) dsum += __shfl_down(dsum, off, 64);
    __shared__ float wsum[4];
    int lane = threadIdx.x & 63, wid = threadIdx.x >> 6;
    if (lane == 0) wsum[wid] = dsum;
    __syncthreads();
    if (threadIdx.x == 0) {
        float b = wsum[0] + wsum[1] + wsum[2] + wsum[3];
        atomicAdd(diff_acc, (double)b);
    }
}

// ---------- seg: gather-style segment sum, one block per code, zero global atomics ----------
__launch_bounds__(256, 4)
__global__ void vq_seg(const float* __restrict__ input,
                       const int* __restrict__ ind,
                       float* __restrict__ esum,
                       float* __restrict__ counts) {
    const int j = blockIdx.x;     // code 0..511
    const int t = threadIdx.x;
    const int wave = t >> 6;      // 0..3
    const int lane = t & 63;      // dim this thread accumulates

    __shared__ int   queue[CHUNK];
    __shared__ int   qn;
    __shared__ float comb[4][64];

    const int4* ind4 = reinterpret_cast<const int4*>(ind);
    float acc = 0.f;
    int   total = 0;

    for (int base = 0; base < N_ROWS; base += CHUNK) {
        if (t == 0) qn = 0;
        __syncthreads();
        // scan this chunk (int4-vectorized); push matching rows
        const int q0 = base >> 2;
#pragma unroll
        for (int rep = 0; rep < CHUNK / 4 / 256; ++rep) {
            int i4 = q0 + rep * 256 + t;
            int4 v = ind4[i4];
            int row = i4 * 4;
            if (v.x == j) { int p = atomicAdd(&qn, 1); queue[p] = row; }
            if (v.y == j) { int p = atomicAdd(&qn, 1); queue[p] = row + 1; }
            if (v.z == j) { int p = atomicAdd(&qn, 1); queue[p] = row + 2; }
            if (v.w == j) { int p = atomicAdd(&qn, 1); queue[p] = row + 3; }
        }
        __syncthreads();
        const int n = qn;
        total += n;
        // drain: each wave takes every 4th row; lane d accumulates dim d (coalesced 256B)
        for (int q = wave; q < n; q += 4) {
            int row = queue[q];
            acc += input[(size_t)row * DIM + lane];
        }
        __syncthreads();   // queue reused next chunk
    }

    comb[wave][lane] = acc;
    __syncthreads();
    if (t < 64) {
        float s = comb[0][t] + comb[1][t] + comb[2][t] + comb[3][t];
        esum[t * N_EMBED + j] = s;          // [d][j] layout, plain store
        if (t == 0) counts[j] = (float)total;
    }
}

// ---------- finalize A: new_cluster_size + n ----------
__global__ void fin_a(const float* __restrict__ cluster_size,
                      const float* __restrict__ counts,
                      float* __restrict__ out_ncs,
                      float* __restrict__ nstore) {
    int t = threadIdx.x;  // 512 threads, 1 block
    float ncs = cluster_size[t] * 0.99f + 0.01f * counts[t];
    out_ncs[t] = ncs;
    __shared__ float red[512];
    red[t] = ncs;
    __syncthreads();
    for (int s = 256; s > 0; s >>= 1) {
        if (t < s) red[t] += red[t + s];
        __syncthreads();
    }
    if (t == 0) nstore[0] = red[0];
}

// ---------- finalize B: EMA + normalize + diff, fully coalesced ----------
__global__ void fin_b(const float* __restrict__ embed_avg,
                      const float* __restrict__ esum,
                      const float* __restrict__ out_ncs,
                      const float* __restrict__ nstore,
                      const double* __restrict__ diff_acc,
                      float* __restrict__ out_ne,
                      float* __restrict__ out_nea,
                      float* __restrict__ out_diff) {
    int e = blockIdx.x * 512 + threadIdx.x;   // 64 blocks -> 32768
    const float EPSF = 1e-5f;
    float n = nstore[0];
    int j = e & (N_EMBED - 1);
    float ncs = out_ncs[j];
    float cs = (ncs + EPSF) / (n + 512.0f * EPSF) * n;
    float es = embed_avg[e] * 0.99f + 0.01f * esum[e];
    out_nea[e] = es;
    out_ne[e] = es / cs;
    if (e == 0) out_diff[0] = (float)(*diff_acc * (1.0 / 8388608.0));
}

extern "C" void kernel_launch(void* const* d_in, const int* in_sizes, int n_in,
                              void* d_out, int out_size, void* d_ws, size_t ws_size,
                              hipStream_t stream) {
    const float* input        = (const float*)d_in[0];
    const float* embed        = (const float*)d_in[1];
    const float* cluster_size = (const float*)d_in[2];
    const float* embed_avg    = (const float*)d_in[3];

    float* out_q    = (float*)d_out;          // 8388608 floats
    float* out_diff = out_q + 8388608;        // 1
    float* out_ind  = out_diff + 1;           // 131072
    float* out_ne   = out_ind + 131072;       // 32768
    float* out_ncs  = out_ne + 32768;         // 512
    float* out_nea  = out_ncs + 512;          // 32768

    // ws layout (~776 KB used)
    char*   ws       = (char*)d_ws;
    double* diff_acc = (double*)ws;                              // [0,8)
    float*  nstore   = (float*)(ws + 64);                        // 1 f32
    float*  counts   = (float*)(ws + 256);                       // 512 f32
    float*  se       = (float*)(ws + 4096);                      // 512 f32
    int*    ind      = (int*)(ws + 8192);                        // 131072 i32 (512 KB)
    float*  esum     = (float*)(ws + 8192 + 524288);             // 32768 f32 (128 KB)
    float*  embed_t  = (float*)(ws + 8192 + 524288 + 131072);    // 32768 f32 (128 KB)

    const size_t need_et = 8192 + 524288 + 131072 + 131072;
    const int have_et = (ws_size >= need_et) ? 1 : 0;

    hipMemsetAsync(ws, 0, 256, stream);   // diff_acc + nstore (counts direct-stored)

    prep_kernel<<<2, 256, 0, stream>>>(embed, se, embed_t, have_et);
    vq_assign<<<1024, 256, 0, stream>>>(input, embed, se, out_ind, ind);
    vq_quant<<<512, 256, 0, stream>>>(input, embed, embed_t, ind, out_q,
                                      diff_acc, have_et);
    vq_seg<<<512, 256, 0, stream>>>(input, ind, esum, counts);
    fin_a<<<1, 512, 0, stream>>>(cluster_size, counts, out_ncs, nstore);
    fin_b<<<64, 512, 0, stream>>>(embed_avg, esum, out_ncs, nstore, diff_acc,
                                  out_ne, out_nea, out_diff);
}